// Round 1
// baseline (859.429 us; speedup 1.0000x reference)
//
#include <hip/hip_runtime.h>

#define T_ 3
#define B_ 4
#define N_ 4096
#define K_ 8
#define BLK 256

// ---------------------------------------------------------------------------
// Block-level sum reduction into lane 0 of wave 0; scratch must hold >=4 floats.
__device__ inline float block_reduce(float v, float* scratch) {
    #pragma unroll
    for (int off = 32; off > 0; off >>= 1) v += __shfl_down(v, off, 64);
    const int lane = threadIdx.x & 63, wid = threadIdx.x >> 6;
    if (lane == 0) scratch[wid] = v;
    __syncthreads();
    float s = 0.f;
    if (threadIdx.x == 0) {
        #pragma unroll
        for (int w = 0; w < BLK / 64; ++w) s += scratch[w];
    }
    return s;  // valid on thread 0 only
}

// ---------------------------------------------------------------------------
// KNN: for each (b, i) find 8 nearest neighbours in source_points[b] (self
// excluded). Stable top-9 (ties -> lower index) matches jax.lax.top_k, and
// self-distance is computed to be exactly 0.0f so slot 0 is always self.
__global__ void knn_kernel(const float* __restrict__ src, int* __restrict__ idx) {
    __shared__ float4 pts[N_];  // 64 KiB: (x, y, z, |p|^2)
    const int b  = blockIdx.x / (N_ / BLK);
    const int m0 = (blockIdx.x % (N_ / BLK)) * BLK;
    const float* sb = src + (size_t)b * N_ * 3;
    for (int j = threadIdx.x; j < N_; j += BLK) {
        float x = sb[j * 3 + 0], y = sb[j * 3 + 1], z = sb[j * 3 + 2];
        pts[j] = make_float4(x, y, z, fmaf(x, x, fmaf(y, y, z * z)));
    }
    __syncthreads();

    const int i = m0 + threadIdx.x;
    const float4 q = pts[i];
    float bd[9];
    int   bi[9];
    #pragma unroll
    for (int p = 0; p < 9; ++p) { bd[p] = 3.4e38f; bi[p] = 0x7fffffff; }

    for (int j = 0; j < N_; ++j) {
        float4 c = pts[j];
        float dot = fmaf(q.x, c.x, fmaf(q.y, c.y, q.z * c.z));
        float d = (q.w + c.w) - 2.0f * dot;  // exactly 0 when j == i
        if (d < bd[8]) {
            // Unrolled stable insertion (strict < keeps earlier = lower index first).
            #pragma unroll
            for (int p = 8; p >= 1; --p) {
                bool here = d < bd[p];
                bool cont = d < bd[p - 1];
                float nd = cont ? bd[p - 1] : d;
                int   ni = cont ? bi[p - 1] : j;
                bd[p] = here ? nd : bd[p];
                bi[p] = here ? ni : bi[p];
            }
            if (d < bd[0]) { bd[0] = d; bi[0] = j; }
        }
    }
    int* op = idx + ((size_t)b * N_ + i) * K_;
    #pragma unroll
    for (int k = 0; k < K_; ++k) op[k] = bi[k + 1];  // drop self
}

// ---------------------------------------------------------------------------
// Chamfer: per (t, b, dir, chunk) block. dir 0: query=dp, db=target (d1);
// dir 1: query=target, db=dp (d2). Accumulates sum(min) * 0.5/B into out.
__global__ void chamfer_kernel(const float* __restrict__ dp_all,
                               const float* __restrict__ tp,
                               float* __restrict__ out) {
    __shared__ float4 pts[N_];  // 64 KiB
    int blk = blockIdx.x;
    const int chunk = blk % (N_ / BLK); blk /= (N_ / BLK);
    const int dir = blk & 1; blk >>= 1;
    const int b = blk % B_;
    const int t = blk / B_;

    const float* dpb = dp_all + ((size_t)t * B_ + b) * (N_ * 3);
    const float* tpb = tp + (size_t)b * (N_ * 3);
    const float* dbase = dir ? dpb : tpb;
    const float* qbase = dir ? tpb : dpb;

    for (int j = threadIdx.x; j < N_; j += BLK) {
        float x = dbase[j * 3 + 0], y = dbase[j * 3 + 1], z = dbase[j * 3 + 2];
        pts[j] = make_float4(x, y, z, fmaf(x, x, fmaf(y, y, z * z)));
    }
    __syncthreads();

    const int i = chunk * BLK + threadIdx.x;
    const float qx = qbase[i * 3 + 0], qy = qbase[i * 3 + 1], qz = qbase[i * 3 + 2];
    const float x2 = fmaf(qx, qx, fmaf(qy, qy, qz * qz));

    float dmin = 3.4e38f;
    #pragma unroll 4
    for (int j = 0; j < N_; ++j) {
        float4 c = pts[j];  // uniform address across the wave -> LDS broadcast
        float dot = fmaf(qx, c.x, fmaf(qy, c.y, qz * c.z));
        dmin = fminf(dmin, fmaf(-2.0f, dot, c.w));  // x2 hoisted (min-monotone)
    }
    float v = x2 + dmin;
    __syncthreads();
    float s = block_reduce(v, (float*)pts);
    if (threadIdx.x == 0) atomicAdd(out, s * (0.5f / B_));
}

// ---------------------------------------------------------------------------
// ARAP: per (t, b, chunk) block, one point per thread, K gathered neighbours.
__global__ void arap_kernel(const float* __restrict__ dp_all,
                            const float* __restrict__ src,
                            const int* __restrict__ idx,
                            float* __restrict__ out) {
    __shared__ float red[BLK / 64];
    int blk = blockIdx.x;
    const int chunk = blk % (N_ / BLK); blk /= (N_ / BLK);
    const int b = blk % B_;
    const int t = blk / B_;
    const int n = chunk * BLK + threadIdx.x;

    const float* dp = dp_all + ((size_t)t * B_ + b) * (N_ * 3);
    const float* sp = src + (size_t)b * (N_ * 3);
    const float px = dp[n * 3], py = dp[n * 3 + 1], pz = dp[n * 3 + 2];
    const float sx = sp[n * 3], sy = sp[n * 3 + 1], sz = sp[n * 3 + 2];
    const int* ip = idx + ((size_t)b * N_ + n) * K_;

    float acc = 0.f;
    #pragma unroll
    for (int k = 0; k < K_; ++k) {
        int j = ip[k];
        float dx = dp[j * 3] - px, dy = dp[j * 3 + 1] - py, dz = dp[j * 3 + 2] - pz;
        float ex = sp[j * 3] - sx, ey = sp[j * 3 + 1] - sy, ez = sp[j * 3 + 2] - sz;
        float dd = sqrtf(fmaf(dx, dx, fmaf(dy, dy, dz * dz)) + 1e-5f);
        float sd = sqrtf(fmaf(ex, ex, fmaf(ey, ey, ez * ez)) + 1e-5f);
        float df = dd - sd;
        acc = fmaf(df, df, acc);
    }
    float s = block_reduce(acc, red);
    if (threadIdx.x == 0) atomicAdd(out, s * (1.0f / B_));
}

// ---------------------------------------------------------------------------
// pd + sp + tran fused. Sum over all t folds: pd=Σdiff²/B, sp=Σ|w|/(B*N),
// tran=Σ m[t,b,r,3]² / B (r in 0..2).
__global__ void small_losses_kernel(const float* __restrict__ drp,
                                    const float* __restrict__ dp,
                                    const float* __restrict__ pw,
                                    const float* __restrict__ rm,
                                    float* __restrict__ out) {
    __shared__ float red[BLK / 64];
    const int PD_N = T_ * B_ * N_ * 3;
    const int SP_N = T_ * B_ * N_;
    const int stride = gridDim.x * blockDim.x;
    const int gid = blockIdx.x * blockDim.x + threadIdx.x;

    float apd = 0.f;
    for (int i = gid; i < PD_N; i += stride) {
        float d = drp[i] - dp[i];
        apd = fmaf(d, d, apd);
    }
    float asp = 0.f;
    for (int i = gid; i < SP_N; i += stride) asp += fabsf(pw[i]);
    float atr = 0.f;
    if (gid < T_ * B_ * 3) {
        int t = gid / (B_ * 3);
        int b = (gid / 3) % B_;
        int r = gid % 3;
        float v = rm[t * B_ * 16 + b * 16 + r * 4 + 3];
        atr = v * v;
    }
    float acc = apd * (1.0f / B_) + asp * (1.0f / (B_ * N_)) + atr * (1.0f / B_);
    float s = block_reduce(acc, red);
    if (threadIdx.x == 0) atomicAdd(out, s);
}

// ---------------------------------------------------------------------------
extern "C" void kernel_launch(void* const* d_in, const int* in_sizes, int n_in,
                              void* d_out, int out_size, void* d_ws, size_t ws_size,
                              hipStream_t stream) {
    const float* pw  = (const float*)d_in[1];  // point_weight [T,B,N,1]
    const float* drp = (const float*)d_in[2];  // deform_rigid_points [T,B,N,3]
    const float* dp  = (const float*)d_in[3];  // deformation_points [T,B,N,3]
    const float* rm  = (const float*)d_in[4];  // rigid_matrix [T,B,4,4]
    const float* sp  = (const float*)d_in[5];  // source_points [B,N,3]
    const float* tp  = (const float*)d_in[6];  // target_points [B,N,3]
    float* out = (float*)d_out;
    int* idx = (int*)d_ws;  // B*N*K ints = 512 KiB

    hipMemsetAsync(out, 0, sizeof(float), stream);

    knn_kernel<<<B_ * (N_ / BLK), BLK, 0, stream>>>(sp, idx);
    chamfer_kernel<<<T_ * B_ * 2 * (N_ / BLK), BLK, 0, stream>>>(dp, tp, out);
    arap_kernel<<<T_ * B_ * (N_ / BLK), BLK, 0, stream>>>(dp, sp, idx, out);
    small_losses_kernel<<<64, BLK, 0, stream>>>(drp, dp, pw, rm, out);
}

// Round 2
// 210.667 us; speedup vs baseline: 4.0796x; 4.0796x over previous
//
#include <hip/hip_runtime.h>

#define T_ 3
#define B_ 4
#define N_ 4096
#define K_ 8

// ---------------------------------------------------------------------------
template <int NW>
__device__ inline float block_reduce(float v, float* scratch) {
    #pragma unroll
    for (int off = 32; off > 0; off >>= 1) v += __shfl_down(v, off, 64);
    const int lane = threadIdx.x & 63, wid = threadIdx.x >> 6;
    if (lane == 0) scratch[wid] = v;
    __syncthreads();
    float s = 0.f;
    if (threadIdx.x == 0) {
        #pragma unroll
        for (int w = 0; w < NW; ++w) s += scratch[w];
    }
    return s;  // valid on thread 0 only
}

// ---------------------------------------------------------------------------
// KNN v2: block = 32 queries x 8 candidate-chunks (512 cands each).
// Grid = B * N/32 = 512 blocks -> 2 blocks/CU at 64 KiB LDS = full machine.
// Self excluded by index; per-chunk top-8 then in-block merge (stable, strict <).
#define KQPB 32
#define KCH 8
#define KCHSZ (N_ / KCH)  // 512

__global__ __launch_bounds__(256) void knn_kernel(const float* __restrict__ src,
                                                  int* __restrict__ idx) {
    __shared__ float4 pts[N_];  // 64 KiB, premultiplied (-2x,-2y,-2z,|c|^2)
    const int b  = blockIdx.x / (N_ / KQPB);
    const int q0 = (blockIdx.x % (N_ / KQPB)) * KQPB;
    const float* sb = src + (size_t)b * N_ * 3;
    for (int j = threadIdx.x; j < N_; j += 256) {
        float x = sb[3 * j], y = sb[3 * j + 1], z = sb[3 * j + 2];
        pts[j] = make_float4(-2.f * x, -2.f * y, -2.f * z, fmaf(x, x, fmaf(y, y, z * z)));
    }
    __syncthreads();

    const int lq = threadIdx.x >> 3;  // 0..31
    const int c  = threadIdx.x & 7;   // chunk 0..7
    const int i  = q0 + lq;
    const float qx = sb[3 * i], qy = sb[3 * i + 1], qz = sb[3 * i + 2];

    float bd[K_];
    int   bi[K_];
    #pragma unroll
    for (int p = 0; p < K_; ++p) { bd[p] = 3.4e38f; bi[p] = 0x7fffffff; }

    const int j0 = c * KCHSZ;
    const int rot = c * 65;  // stagger so the 8 wave addresses hit distinct bank quads
    #pragma unroll 4
    for (int jj = 0; jj < KCHSZ; ++jj) {
        const int j = j0 + ((jj + rot) & (KCHSZ - 1));
        float4 cd = pts[j];
        // relative distance: |c|^2 - 2 q.c  (|q|^2 shift dropped; order-invariant)
        float d = fmaf(qx, cd.x, fmaf(qy, cd.y, fmaf(qz, cd.z, cd.w)));
        if (d < bd[K_ - 1] && j != i) {
            #pragma unroll
            for (int p = K_ - 1; p >= 1; --p) {
                bool here = d < bd[p];
                bool cont = d < bd[p - 1];
                float nd = cont ? bd[p - 1] : d;
                int   ni = cont ? bi[p - 1] : j;
                bd[p] = here ? nd : bd[p];
                bi[p] = here ? ni : bi[p];
            }
            if (d < bd[0]) { bd[0] = d; bi[0] = j; }
        }
    }
    __syncthreads();

    // Reuse pts as merge scratch: 17 floats/thread (pad breaks 32-way conflicts).
    float* fb = (float*)pts;
    int*   ib = (int*)pts;
    const int base = threadIdx.x * 17;
    #pragma unroll
    for (int p = 0; p < K_; ++p) { fb[base + p] = bd[p]; ib[base + 8 + p] = bi[p]; }
    __syncthreads();

    if (threadIdx.x < KQPB) {
        const int qm = q0 + threadIdx.x;
        float md[K_]; int mi[K_];
        const int b0 = (threadIdx.x * 8) * 17;
        #pragma unroll
        for (int p = 0; p < K_; ++p) { md[p] = fb[b0 + p]; mi[p] = ib[b0 + 8 + p]; }
        for (int cc = 1; cc < KCH; ++cc) {
            const int bc = (threadIdx.x * 8 + cc) * 17;
            #pragma unroll
            for (int e = 0; e < K_; ++e) {
                float d = fb[bc + e];
                if (d >= md[K_ - 1]) break;  // chunk list sorted ascending
                int j = ib[bc + 8 + e];
                #pragma unroll
                for (int p = K_ - 1; p >= 1; --p) {
                    bool here = d < md[p];
                    bool cont = d < md[p - 1];
                    float nd = cont ? md[p - 1] : d;
                    int   ni = cont ? mi[p - 1] : j;
                    md[p] = here ? nd : md[p];
                    mi[p] = here ? ni : mi[p];
                }
                if (d < md[0]) { md[0] = d; mi[0] = j; }
            }
        }
        int* op = idx + ((size_t)b * N_ + qm) * K_;
        #pragma unroll
        for (int k = 0; k < K_; ++k) op[k] = mi[k];
    }
}

// ---------------------------------------------------------------------------
// Chamfer v2: 4 queries/thread (amortize ds_read), candidate chunks of 512
// (8 KiB LDS), premultiplied candidates (3 fma + 1 min per pair).
// Writes per-chunk partial mins of (|c|^2 - 2 q.c) to ws; merge adds |q|^2.
#define CCH 8
#define CCHSZ (N_ / CCH)  // 512
#define CQ 4

__global__ __launch_bounds__(256) void chamfer_kernel(const float* __restrict__ dp_all,
                                                      const float* __restrict__ tp,
                                                      float* __restrict__ pmin) {
    __shared__ float4 pts[CCHSZ];  // 8 KiB
    int blk = blockIdx.x;
    const int cc = blk & (CCH - 1); blk >>= 3;
    const int qc = blk & 3;         blk >>= 2;
    const int tbd = blk;            // ((t*B+b)*2+dir)
    const int dir = tbd & 1;
    const int tb  = tbd >> 1;
    const int b = tb % B_, t = tb / B_;

    const float* dpb = dp_all + ((size_t)(t * B_ + b)) * N_ * 3;
    const float* tpb = tp + (size_t)b * N_ * 3;
    const float* dbase = dir ? dpb : tpb;
    const float* qbase = dir ? tpb : dpb;

    for (int j = threadIdx.x; j < CCHSZ; j += 256) {
        int jg = cc * CCHSZ + j;
        float x = dbase[3 * jg], y = dbase[3 * jg + 1], z = dbase[3 * jg + 2];
        pts[j] = make_float4(-2.f * x, -2.f * y, -2.f * z, fmaf(x, x, fmaf(y, y, z * z)));
    }
    __syncthreads();

    float qx[CQ], qy[CQ], qz[CQ], m[CQ];
    #pragma unroll
    for (int u = 0; u < CQ; ++u) {
        int q = qc * 1024 + u * 256 + threadIdx.x;
        qx[u] = qbase[3 * q]; qy[u] = qbase[3 * q + 1]; qz[u] = qbase[3 * q + 2];
        m[u] = 3.4e38f;
    }
    #pragma unroll 4
    for (int j = 0; j < CCHSZ; ++j) {
        float4 cd = pts[j];  // wave-uniform -> LDS broadcast
        #pragma unroll
        for (int u = 0; u < CQ; ++u)
            m[u] = fminf(m[u], fmaf(qx[u], cd.x, fmaf(qy[u], cd.y, fmaf(qz[u], cd.z, cd.w))));
    }
    #pragma unroll
    for (int u = 0; u < CQ; ++u)
        pmin[((size_t)tbd * CCH + cc) * N_ + qc * 1024 + u * 256 + threadIdx.x] = m[u];
}

__global__ __launch_bounds__(256) void chamfer_merge_kernel(const float* __restrict__ dp_all,
                                                            const float* __restrict__ tp,
                                                            const float* __restrict__ pmin,
                                                            float* __restrict__ out) {
    __shared__ float red[4];
    const int tbd = blockIdx.x >> 4;
    const int q = (blockIdx.x & 15) * 256 + threadIdx.x;
    const int dir = tbd & 1, tb = tbd >> 1, b = tb % B_, t = tb / B_;
    const float* qbase = dir ? tp + (size_t)b * N_ * 3
                             : dp_all + ((size_t)(t * B_ + b)) * N_ * 3;
    float m = 3.4e38f;
    #pragma unroll
    for (int cc = 0; cc < CCH; ++cc)
        m = fminf(m, pmin[((size_t)tbd * CCH + cc) * N_ + q]);
    float x = qbase[3 * q], y = qbase[3 * q + 1], z = qbase[3 * q + 2];
    float v = fmaf(x, x, fmaf(y, y, z * z)) + m;
    float s = block_reduce<4>(v, red);
    if (threadIdx.x == 0) atomicAdd(out, s * (0.5f / B_));
}

// ---------------------------------------------------------------------------
// ARAP: 128-thread blocks -> 384 blocks for latency hiding on the gathers.
#define ABLK 128
__global__ __launch_bounds__(ABLK) void arap_kernel(const float* __restrict__ dp_all,
                                                    const float* __restrict__ src,
                                                    const int* __restrict__ idx,
                                                    float* __restrict__ out) {
    __shared__ float red[2];
    int blk = blockIdx.x;
    const int chunk = blk % (N_ / ABLK); blk /= (N_ / ABLK);
    const int b = blk % B_;
    const int t = blk / B_;
    const int n = chunk * ABLK + threadIdx.x;

    const float* dp = dp_all + ((size_t)t * B_ + b) * (N_ * 3);
    const float* sp = src + (size_t)b * (N_ * 3);
    const float px = dp[n * 3], py = dp[n * 3 + 1], pz = dp[n * 3 + 2];
    const float sx = sp[n * 3], sy = sp[n * 3 + 1], sz = sp[n * 3 + 2];
    const int* ip = idx + ((size_t)b * N_ + n) * K_;

    float acc = 0.f;
    #pragma unroll
    for (int k = 0; k < K_; ++k) {
        int j = ip[k];
        float dx = dp[j * 3] - px, dy = dp[j * 3 + 1] - py, dz = dp[j * 3 + 2] - pz;
        float ex = sp[j * 3] - sx, ey = sp[j * 3 + 1] - sy, ez = sp[j * 3 + 2] - sz;
        float dd = sqrtf(fmaf(dx, dx, fmaf(dy, dy, dz * dz)) + 1e-5f);
        float sd = sqrtf(fmaf(ex, ex, fmaf(ey, ey, ez * ez)) + 1e-5f);
        float df = dd - sd;
        acc = fmaf(df, df, acc);
    }
    float s = block_reduce<2>(acc, red);
    if (threadIdx.x == 0) atomicAdd(out, s * (1.0f / B_));
}

// ---------------------------------------------------------------------------
__global__ __launch_bounds__(256) void small_losses_kernel(const float* __restrict__ drp,
                                                           const float* __restrict__ dp,
                                                           const float* __restrict__ pw,
                                                           const float* __restrict__ rm,
                                                           float* __restrict__ out) {
    __shared__ float red[4];
    const int PD_N = T_ * B_ * N_ * 3;
    const int SP_N = T_ * B_ * N_;
    const int stride = gridDim.x * blockDim.x;
    const int gid = blockIdx.x * blockDim.x + threadIdx.x;

    float apd = 0.f;
    for (int i = gid; i < PD_N; i += stride) {
        float d = drp[i] - dp[i];
        apd = fmaf(d, d, apd);
    }
    float asp = 0.f;
    for (int i = gid; i < SP_N; i += stride) asp += fabsf(pw[i]);
    float atr = 0.f;
    if (gid < T_ * B_ * 3) {
        int t = gid / (B_ * 3);
        int b = (gid / 3) % B_;
        int r = gid % 3;
        float v = rm[t * B_ * 16 + b * 16 + r * 4 + 3];
        atr = v * v;
    }
    float acc = apd * (1.0f / B_) + asp * (1.0f / (B_ * N_)) + atr * (1.0f / B_);
    float s = block_reduce<4>(acc, red);
    if (threadIdx.x == 0) atomicAdd(out, s);
}

// ---------------------------------------------------------------------------
extern "C" void kernel_launch(void* const* d_in, const int* in_sizes, int n_in,
                              void* d_out, int out_size, void* d_ws, size_t ws_size,
                              hipStream_t stream) {
    const float* pw  = (const float*)d_in[1];
    const float* drp = (const float*)d_in[2];
    const float* dp  = (const float*)d_in[3];
    const float* rm  = (const float*)d_in[4];
    const float* sp  = (const float*)d_in[5];
    const float* tp  = (const float*)d_in[6];
    float* out = (float*)d_out;

    int*   idx  = (int*)d_ws;                                  // 512 KiB
    float* pmin = (float*)((char*)d_ws + (size_t)B_ * N_ * K_ * 4);  // 24*8*4096 floats = 3 MiB

    hipMemsetAsync(out, 0, sizeof(float), stream);

    knn_kernel<<<B_ * (N_ / KQPB), 256, 0, stream>>>(sp, idx);
    chamfer_kernel<<<T_ * B_ * 2 * 4 * CCH, 256, 0, stream>>>(dp, tp, pmin);
    chamfer_merge_kernel<<<T_ * B_ * 2 * (N_ / 256), 256, 0, stream>>>(dp, tp, pmin, out);
    arap_kernel<<<T_ * B_ * (N_ / ABLK), ABLK, 0, stream>>>(dp, sp, idx, out);
    small_losses_kernel<<<128, 256, 0, stream>>>(drp, dp, pw, rm, out);
}

// Round 3
// 169.282 us; speedup vs baseline: 5.0769x; 1.2445x over previous
//
#include <hip/hip_runtime.h>

#define T_ 3
#define B_ 4
#define N_ 4096
#define K_ 8

// ---------------------------------------------------------------------------
template <int NW>
__device__ inline float block_reduce(float v, float* scratch) {
    #pragma unroll
    for (int off = 32; off > 0; off >>= 1) v += __shfl_down(v, off, 64);
    const int lane = threadIdx.x & 63, wid = threadIdx.x >> 6;
    if (lane == 0) scratch[wid] = v;
    __syncthreads();
    float s = 0.f;
    if (threadIdx.x == 0) {
        #pragma unroll
        for (int w = 0; w < NW; ++w) s += scratch[w];
    }
    return s;  // valid on thread 0 only
}

// ---------------------------------------------------------------------------
// KNN v3: packed sortable-uint top-8, branch-free 16-op bubble per candidate.
// packed = (float_bits(d) & 0xFFFFF000) | j   (d >= 0 so bits are monotone;
// 12 dropped mantissa bits only affect ordering of near-equal distances,
// which perturbs the loss by O(1) vs threshold 2805).
// Block = 32 queries x 8 candidate-chunks (512 each); grid = 512 blocks.
#define KQPB 32
#define KCH 8
#define KCHSZ (N_ / KCH)  // 512

__global__ __launch_bounds__(256) void knn_kernel(const float* __restrict__ src,
                                                  int* __restrict__ idx) {
    __shared__ float4 pts[N_];  // 64 KiB, premultiplied (-2x,-2y,-2z,|c|^2)
    const int b  = blockIdx.x / (N_ / KQPB);
    const int q0 = (blockIdx.x % (N_ / KQPB)) * KQPB;
    const float* sb = src + (size_t)b * N_ * 3;
    for (int j = threadIdx.x; j < N_; j += 256) {
        float x = sb[3 * j], y = sb[3 * j + 1], z = sb[3 * j + 2];
        pts[j] = make_float4(-2.f * x, -2.f * y, -2.f * z, fmaf(x, x, fmaf(y, y, z * z)));
    }
    __syncthreads();

    const int lq = threadIdx.x >> 3;  // query slot 0..31
    const int c  = threadIdx.x & 7;   // chunk 0..7
    const int i  = q0 + lq;
    const float qx = sb[3 * i], qy = sb[3 * i + 1], qz = sb[3 * i + 2];
    const float q2 = fmaf(qx, qx, fmaf(qy, qy, qz * qz));

    unsigned m[K_];
    #pragma unroll
    for (int p = 0; p < K_; ++p) m[p] = 0xFFFFFFFFu;

    const int j0 = c * KCHSZ;
    const int rot = c * 65;  // (jj + 65c) % 8 distinct across c -> conflict-free b128
    #pragma unroll 4
    for (int jj = 0; jj < KCHSZ; ++jj) {
        const int j = j0 + ((jj + rot) & (KCHSZ - 1));
        float4 cd = pts[j];
        float d = fmaf(qx, cd.x, fmaf(qy, cd.y, fmaf(qz, cd.z, cd.w))) + q2;  // >= 0
        unsigned pu = (__float_as_uint(d) & 0xFFFFF000u) | (unsigned)j;
        pu = (j == i) ? 0xFFFFFFFFu : pu;  // exclude self
        // branch-free sorted-ascending bubble (keeps 8 smallest)
        unsigned t = pu;
        #pragma unroll
        for (int p = 0; p < K_; ++p) {
            unsigned lo = min(m[p], t);
            t = max(m[p], t);
            m[p] = lo;
        }
    }
    __syncthreads();

    // Merge scratch reused from pts, transposed layout: element e of chunk c of
    // query tq at sm[(c*8+e)*33 + tq] -> across tq stride 1 (conflict-free).
    unsigned* sm = (unsigned*)pts;
    #pragma unroll
    for (int e = 0; e < K_; ++e) sm[(c * 8 + e) * 33 + lq] = m[e];
    __syncthreads();

    if (threadIdx.x < KQPB) {
        const int tq = threadIdx.x;
        unsigned md[K_];
        #pragma unroll
        for (int e = 0; e < K_; ++e) md[e] = sm[e * 33 + tq];  // chunk 0 (sorted)
        for (int cc = 1; cc < KCH; ++cc) {
            #pragma unroll
            for (int e = 0; e < K_; ++e) {
                unsigned v = sm[(cc * 8 + e) * 33 + tq];
                if (v >= md[K_ - 1]) break;  // source list sorted ascending
                unsigned t = v;
                #pragma unroll
                for (int p = 0; p < K_; ++p) {
                    unsigned lo = min(md[p], t);
                    t = max(md[p], t);
                    md[p] = lo;
                }
            }
        }
        int* op = idx + ((size_t)b * N_ + q0 + tq) * K_;
        #pragma unroll
        for (int k = 0; k < K_; ++k) op[k] = (int)(md[k] & 0xFFFu);
    }
}

// ---------------------------------------------------------------------------
// Chamfer v3: 8 queries/thread, candidate chunks of 256 (4 KiB LDS), grid 768.
// Per-chunk partial mins of (|c|^2 - 2 q.c) merged via atomicMin on sortable
// uint bits (value may be negative; |q|^2 folded in at merge).
#define CCH 16
#define CCHSZ (N_ / CCH)  // 256
#define CQ 8

__device__ inline unsigned f2sortable(float f) {
    unsigned b = __float_as_uint(f);
    return b ^ ((unsigned)((int)b >> 31) | 0x80000000u);
}
__device__ inline float sortable2f(unsigned u) {
    unsigned b = (u & 0x80000000u) ? (u ^ 0x80000000u) : ~u;
    return __uint_as_float(b);
}

__global__ __launch_bounds__(256) void chamfer_kernel(const float* __restrict__ dp_all,
                                                      const float* __restrict__ tp,
                                                      unsigned* __restrict__ cmin) {
    __shared__ float4 pts[CCHSZ];  // 4 KiB
    int blk = blockIdx.x;
    const int cc = blk & (CCH - 1); blk >>= 4;
    const int qc = blk & 1;         blk >>= 1;
    const int tbd = blk;            // ((t*B+b)*2+dir)
    const int dir = tbd & 1;
    const int tb  = tbd >> 1;
    const int b = tb % B_, t = tb / B_;

    const float* dpb = dp_all + ((size_t)(t * B_ + b)) * N_ * 3;
    const float* tpb = tp + (size_t)b * N_ * 3;
    const float* dbase = dir ? dpb : tpb;  // candidates
    const float* qbase = dir ? tpb : dpb;  // queries

    for (int j = threadIdx.x; j < CCHSZ; j += 256) {
        int jg = cc * CCHSZ + j;
        float x = dbase[3 * jg], y = dbase[3 * jg + 1], z = dbase[3 * jg + 2];
        pts[j] = make_float4(-2.f * x, -2.f * y, -2.f * z, fmaf(x, x, fmaf(y, y, z * z)));
    }
    __syncthreads();

    float qx[CQ], qy[CQ], qz[CQ], m[CQ];
    #pragma unroll
    for (int u = 0; u < CQ; ++u) {
        int q = qc * 2048 + u * 256 + threadIdx.x;
        qx[u] = qbase[3 * q]; qy[u] = qbase[3 * q + 1]; qz[u] = qbase[3 * q + 2];
        m[u] = 3.4e38f;
    }
    #pragma unroll 2
    for (int j = 0; j < CCHSZ; ++j) {
        float4 cd = pts[j];  // wave-uniform -> LDS broadcast
        #pragma unroll
        for (int u = 0; u < CQ; ++u)
            m[u] = fminf(m[u], fmaf(qx[u], cd.x, fmaf(qy[u], cd.y, fmaf(qz[u], cd.z, cd.w))));
    }
    unsigned* cm = cmin + (size_t)tbd * N_ + qc * 2048;
    #pragma unroll
    for (int u = 0; u < CQ; ++u)
        atomicMin(&cm[u * 256 + threadIdx.x], f2sortable(m[u]));
}

__global__ __launch_bounds__(256) void chamfer_merge_kernel(const float* __restrict__ dp_all,
                                                            const float* __restrict__ tp,
                                                            const unsigned* __restrict__ cmin,
                                                            float* __restrict__ out) {
    __shared__ float red[4];
    const int tbd = blockIdx.x >> 4;
    const int q = (blockIdx.x & 15) * 256 + threadIdx.x;
    const int dir = tbd & 1, tb = tbd >> 1, b = tb % B_, t = tb / B_;
    const float* qbase = dir ? tp + (size_t)b * N_ * 3
                             : dp_all + ((size_t)(t * B_ + b)) * N_ * 3;
    float mrel = sortable2f(cmin[(size_t)tbd * N_ + q]);
    float x = qbase[3 * q], y = qbase[3 * q + 1], z = qbase[3 * q + 2];
    float v = fmaf(x, x, fmaf(y, y, z * z)) + mrel;  // add |q|^2 (min-monotone shift)
    float s = block_reduce<4>(v, red);
    if (threadIdx.x == 0) atomicAdd(out, s * (0.5f / B_));
}

// ---------------------------------------------------------------------------
#define ABLK 128
__global__ __launch_bounds__(ABLK) void arap_kernel(const float* __restrict__ dp_all,
                                                    const float* __restrict__ src,
                                                    const int* __restrict__ idx,
                                                    float* __restrict__ out) {
    __shared__ float red[2];
    int blk = blockIdx.x;
    const int chunk = blk % (N_ / ABLK); blk /= (N_ / ABLK);
    const int b = blk % B_;
    const int t = blk / B_;
    const int n = chunk * ABLK + threadIdx.x;

    const float* dp = dp_all + ((size_t)t * B_ + b) * (N_ * 3);
    const float* sp = src + (size_t)b * (N_ * 3);
    const float px = dp[n * 3], py = dp[n * 3 + 1], pz = dp[n * 3 + 2];
    const float sx = sp[n * 3], sy = sp[n * 3 + 1], sz = sp[n * 3 + 2];
    const int* ip = idx + ((size_t)b * N_ + n) * K_;

    float acc = 0.f;
    #pragma unroll
    for (int k = 0; k < K_; ++k) {
        int j = ip[k];
        float dx = dp[j * 3] - px, dy = dp[j * 3 + 1] - py, dz = dp[j * 3 + 2] - pz;
        float ex = sp[j * 3] - sx, ey = sp[j * 3 + 1] - sy, ez = sp[j * 3 + 2] - sz;
        float dd = sqrtf(fmaf(dx, dx, fmaf(dy, dy, dz * dz)) + 1e-5f);
        float sd = sqrtf(fmaf(ex, ex, fmaf(ey, ey, ez * ez)) + 1e-5f);
        float df = dd - sd;
        acc = fmaf(df, df, acc);
    }
    float s = block_reduce<2>(acc, red);
    if (threadIdx.x == 0) atomicAdd(out, s * (1.0f / B_));
}

// ---------------------------------------------------------------------------
__global__ __launch_bounds__(256) void small_losses_kernel(const float* __restrict__ drp,
                                                           const float* __restrict__ dp,
                                                           const float* __restrict__ pw,
                                                           const float* __restrict__ rm,
                                                           float* __restrict__ out) {
    __shared__ float red[4];
    const int PD_N = T_ * B_ * N_ * 3;
    const int SP_N = T_ * B_ * N_;
    const int stride = gridDim.x * blockDim.x;
    const int gid = blockIdx.x * blockDim.x + threadIdx.x;

    float apd = 0.f;
    for (int i = gid; i < PD_N; i += stride) {
        float d = drp[i] - dp[i];
        apd = fmaf(d, d, apd);
    }
    float asp = 0.f;
    for (int i = gid; i < SP_N; i += stride) asp += fabsf(pw[i]);
    float atr = 0.f;
    if (gid < T_ * B_ * 3) {
        int t = gid / (B_ * 3);
        int b = (gid / 3) % B_;
        int r = gid % 3;
        float v = rm[t * B_ * 16 + b * 16 + r * 4 + 3];
        atr = v * v;
    }
    float acc = apd * (1.0f / B_) + asp * (1.0f / (B_ * N_)) + atr * (1.0f / B_);
    float s = block_reduce<4>(acc, red);
    if (threadIdx.x == 0) atomicAdd(out, s);
}

// ---------------------------------------------------------------------------
extern "C" void kernel_launch(void* const* d_in, const int* in_sizes, int n_in,
                              void* d_out, int out_size, void* d_ws, size_t ws_size,
                              hipStream_t stream) {
    const float* pw  = (const float*)d_in[1];
    const float* drp = (const float*)d_in[2];
    const float* dp  = (const float*)d_in[3];
    const float* rm  = (const float*)d_in[4];
    const float* sp  = (const float*)d_in[5];
    const float* tp  = (const float*)d_in[6];
    float* out = (float*)d_out;

    int*      idx  = (int*)d_ws;                                      // 512 KiB
    unsigned* cmin = (unsigned*)((char*)d_ws + (size_t)B_ * N_ * K_ * 4);  // 24*4096*4 = 384 KiB

    hipMemsetAsync(out, 0, sizeof(float), stream);
    hipMemsetAsync(cmin, 0xFF, (size_t)T_ * B_ * 2 * N_ * 4, stream);

    knn_kernel<<<B_ * (N_ / KQPB), 256, 0, stream>>>(sp, idx);
    chamfer_kernel<<<T_ * B_ * 2 * 2 * CCH, 256, 0, stream>>>(dp, tp, cmin);
    chamfer_merge_kernel<<<T_ * B_ * 2 * (N_ / 256), 256, 0, stream>>>(dp, tp, cmin, out);
    arap_kernel<<<T_ * B_ * (N_ / ABLK), ABLK, 0, stream>>>(dp, sp, idx, out);
    small_losses_kernel<<<128, 256, 0, stream>>>(drp, dp, pw, rm, out);
}

// Round 4
// 156.188 us; speedup vs baseline: 5.5025x; 1.0838x over previous
//
#include <hip/hip_runtime.h>

#define T_ 3
#define B_ 4
#define N_ 4096
#define K_ 8

// ---------------------------------------------------------------------------
template <int NW>
__device__ inline float block_reduce(float v, float* scratch) {
    #pragma unroll
    for (int off = 32; off > 0; off >>= 1) v += __shfl_down(v, off, 64);
    const int lane = threadIdx.x & 63, wid = threadIdx.x >> 6;
    if (lane == 0) scratch[wid] = v;
    __syncthreads();
    float s = 0.f;
    if (threadIdx.x == 0) {
        #pragma unroll
        for (int w = 0; w < NW; ++w) s += scratch[w];
    }
    return s;  // valid on thread 0 only
}

__device__ inline unsigned f2sortable(float f) {
    unsigned b = __float_as_uint(f);
    return b ^ ((unsigned)((int)b >> 31) | 0x80000000u);
}
__device__ inline float sortable2f(unsigned u) {
    unsigned b = (u & 0x80000000u) ? (u ^ 0x80000000u) : ~u;
    return __uint_as_float(b);
}

// ---------------------------------------------------------------------------
// KNN v4: 32 queries/block, candidates streamed in 4 windows of 1024
// (16 KiB LDS -> 6 blocks/CU). Lane-group c (tid&7) scans j == c (mod 8):
// linear 128 B stride -> ds_read_b128 immediate offsets, banks 4c..4c+3
// per group -> conflict-free. Packed sortable top-8, branch-free bubble.
// Also initializes cmin (0xFF) and out (0.0) for the later kernels.
#define KQPB 32
#define KWIN 1024

__global__ __launch_bounds__(256, 6) void knn_kernel(const float* __restrict__ src,
                                                     int* __restrict__ idx,
                                                     unsigned* __restrict__ cmin,
                                                     float* __restrict__ out) {
    __shared__ float4 win[KWIN];  // 16 KiB
    // Piggyback inits (runs before chamfer/finalize in stream order).
    const int g = blockIdx.x * 256 + threadIdx.x;
    if (g < T_ * B_ * 2 * N_) cmin[g] = 0xFFFFFFFFu;
    if (g == 0) *out = 0.f;

    const int b  = blockIdx.x / (N_ / KQPB);
    const int q0 = (blockIdx.x % (N_ / KQPB)) * KQPB;
    const float* sb = src + (size_t)b * N_ * 3;

    const int lq = threadIdx.x >> 3;  // query slot 0..31
    const int c  = threadIdx.x & 7;   // residue class 0..7
    const int i  = q0 + lq;
    const float qx = sb[3 * i], qy = sb[3 * i + 1], qz = sb[3 * i + 2];
    const float q2 = fmaf(qx, qx, fmaf(qy, qy, qz * qz));

    unsigned m[K_];
    #pragma unroll
    for (int p = 0; p < K_; ++p) m[p] = 0xFFFFFFFFu;

    for (int w = 0; w < N_ / KWIN; ++w) {
        __syncthreads();  // readers of previous window done
        for (int j = threadIdx.x; j < KWIN; j += 256) {
            int jg = w * KWIN + j;
            float x = sb[3 * jg], y = sb[3 * jg + 1], z = sb[3 * jg + 2];
            win[j] = make_float4(-2.f * x, -2.f * y, -2.f * z, fmaf(x, x, fmaf(y, y, z * z)));
        }
        __syncthreads();

        #pragma unroll 8
        for (int jj = 0; jj < KWIN / 8; ++jj) {
            float4 cd = win[8 * jj + c];
            float d = fmaf(qx, cd.x, fmaf(qy, cd.y, fmaf(qz, cd.z, cd.w))) + q2;  // >= 0
            const int jglob = w * KWIN + 8 * jj + c;
            unsigned pu = (__float_as_uint(d) & 0xFFFFF000u) | (unsigned)jglob;
            pu = (jglob == i) ? 0xFFFFFFFFu : pu;  // exclude self
            unsigned t = pu;
            #pragma unroll
            for (int p = 0; p < K_; ++p) {  // keep 8 smallest, sorted
                unsigned lo = min(m[p], t);
                t = max(m[p], t);
                m[p] = lo;
            }
        }
    }
    __syncthreads();

    // Merge scratch in win: element e of class c of query tq at (c*8+e)*33+tq.
    unsigned* sm = (unsigned*)win;
    #pragma unroll
    for (int e = 0; e < K_; ++e) sm[(c * 8 + e) * 33 + lq] = m[e];
    __syncthreads();

    if (threadIdx.x < KQPB) {
        const int tq = threadIdx.x;
        unsigned md[K_];
        #pragma unroll
        for (int e = 0; e < K_; ++e) md[e] = sm[e * 33 + tq];  // class 0 (sorted)
        for (int cc = 1; cc < 8; ++cc) {
            #pragma unroll
            for (int e = 0; e < K_; ++e) {
                unsigned v = sm[(cc * 8 + e) * 33 + tq];
                if (v >= md[K_ - 1]) break;  // source sorted ascending
                unsigned t = v;
                #pragma unroll
                for (int p = 0; p < K_; ++p) {
                    unsigned lo = min(md[p], t);
                    t = max(md[p], t);
                    md[p] = lo;
                }
            }
        }
        int* op = idx + ((size_t)b * N_ + q0 + tq) * K_;
        #pragma unroll
        for (int k = 0; k < K_; ++k) op[k] = (int)(md[k] & 0xFFFu);
    }
}

// ---------------------------------------------------------------------------
// Chamfer: 8 queries/thread, 256-candidate chunks (4 KiB LDS), grid 768.
// Partial mins of (|c|^2 - 2 q.c) merged by atomicMin on sortable bits.
#define CCH 16
#define CCHSZ (N_ / CCH)  // 256
#define CQ 8

__global__ __launch_bounds__(256) void chamfer_kernel(const float* __restrict__ dp_all,
                                                      const float* __restrict__ tp,
                                                      unsigned* __restrict__ cmin) {
    __shared__ float4 pts[CCHSZ];  // 4 KiB
    int blk = blockIdx.x;
    const int cc = blk & (CCH - 1); blk >>= 4;
    const int qc = blk & 1;         blk >>= 1;
    const int tbd = blk;            // ((t*B+b)*2+dir)
    const int dir = tbd & 1;
    const int tb  = tbd >> 1;
    const int b = tb % B_, t = tb / B_;

    const float* dpb = dp_all + ((size_t)(t * B_ + b)) * N_ * 3;
    const float* tpb = tp + (size_t)b * N_ * 3;
    const float* dbase = dir ? dpb : tpb;  // candidates
    const float* qbase = dir ? tpb : dpb;  // queries

    if (threadIdx.x < CCHSZ) {
        int jg = cc * CCHSZ + threadIdx.x;
        float x = dbase[3 * jg], y = dbase[3 * jg + 1], z = dbase[3 * jg + 2];
        pts[threadIdx.x] = make_float4(-2.f * x, -2.f * y, -2.f * z,
                                       fmaf(x, x, fmaf(y, y, z * z)));
    }
    __syncthreads();

    float qx[CQ], qy[CQ], qz[CQ], m[CQ];
    #pragma unroll
    for (int u = 0; u < CQ; ++u) {
        int q = qc * 2048 + u * 256 + threadIdx.x;
        qx[u] = qbase[3 * q]; qy[u] = qbase[3 * q + 1]; qz[u] = qbase[3 * q + 2];
        m[u] = 3.4e38f;
    }
    #pragma unroll 2
    for (int j = 0; j < CCHSZ; ++j) {
        float4 cd = pts[j];  // wave-uniform -> LDS broadcast
        #pragma unroll
        for (int u = 0; u < CQ; ++u)
            m[u] = fminf(m[u], fmaf(qx[u], cd.x, fmaf(qy[u], cd.y, fmaf(qz[u], cd.z, cd.w))));
    }
    unsigned* cm = cmin + (size_t)tbd * N_ + qc * 2048;
    #pragma unroll
    for (int u = 0; u < CQ; ++u)
        atomicMin(&cm[u * 256 + threadIdx.x], f2sortable(m[u]));
}

// ---------------------------------------------------------------------------
// Finalize: one kernel, three block roles (wave-uniform branch):
//   [0,384)   chamfer merge: add |q|^2, reduce, atomicAdd * 0.5/B
//   [384,576) arap
//   [576,608) pd + sp + tran grid-stride
__global__ __launch_bounds__(256) void finalize_kernel(const float* __restrict__ dp_all,
                                                       const float* __restrict__ tp,
                                                       const float* __restrict__ src,
                                                       const int* __restrict__ idx,
                                                       const unsigned* __restrict__ cmin,
                                                       const float* __restrict__ drp,
                                                       const float* __restrict__ pw,
                                                       const float* __restrict__ rm,
                                                       float* __restrict__ out) {
    __shared__ float red[4];
    const int blk = blockIdx.x;

    if (blk < 384) {  // ---- chamfer merge
        const int tbd = blk >> 4;
        const int q = (blk & 15) * 256 + threadIdx.x;
        const int dir = tbd & 1, tb = tbd >> 1, b = tb % B_, t = tb / B_;
        const float* qbase = dir ? tp + (size_t)b * N_ * 3
                                 : dp_all + ((size_t)(t * B_ + b)) * N_ * 3;
        float mrel = sortable2f(cmin[(size_t)tbd * N_ + q]);
        float x = qbase[3 * q], y = qbase[3 * q + 1], z = qbase[3 * q + 2];
        float v = fmaf(x, x, fmaf(y, y, z * z)) + mrel;
        float s = block_reduce<4>(v, red);
        if (threadIdx.x == 0) atomicAdd(out, s * (0.5f / B_));
    } else if (blk < 576) {  // ---- arap
        const int ab = blk - 384;
        const int chunk = ab & 15;
        const int tb = ab >> 4;
        const int b = tb % B_, t = tb / B_;
        const int n = chunk * 256 + threadIdx.x;
        const float* dp = dp_all + ((size_t)t * B_ + b) * (N_ * 3);
        const float* sp = src + (size_t)b * (N_ * 3);
        const float px = dp[n * 3], py = dp[n * 3 + 1], pz = dp[n * 3 + 2];
        const float sx = sp[n * 3], sy = sp[n * 3 + 1], sz = sp[n * 3 + 2];
        const int* ip = idx + ((size_t)b * N_ + n) * K_;
        float acc = 0.f;
        #pragma unroll
        for (int k = 0; k < K_; ++k) {
            int j = ip[k];
            float dx = dp[j * 3] - px, dy = dp[j * 3 + 1] - py, dz = dp[j * 3 + 2] - pz;
            float ex = sp[j * 3] - sx, ey = sp[j * 3 + 1] - sy, ez = sp[j * 3 + 2] - sz;
            float dd = sqrtf(fmaf(dx, dx, fmaf(dy, dy, dz * dz)) + 1e-5f);
            float sd = sqrtf(fmaf(ex, ex, fmaf(ey, ey, ez * ez)) + 1e-5f);
            float df = dd - sd;
            acc = fmaf(df, df, acc);
        }
        float s = block_reduce<4>(acc, red);
        if (threadIdx.x == 0) atomicAdd(out, s * (1.0f / B_));
    } else {  // ---- pd + sp + tran
        const int PD_N = T_ * B_ * N_ * 3;
        const int SP_N = T_ * B_ * N_;
        const int stride = 32 * 256;
        const int gid = (blk - 576) * 256 + threadIdx.x;
        float apd = 0.f;
        for (int i = gid; i < PD_N; i += stride) {
            float d = drp[i] - dp_all[i];
            apd = fmaf(d, d, apd);
        }
        float asp = 0.f;
        for (int i = gid; i < SP_N; i += stride) asp += fabsf(pw[i]);
        float atr = 0.f;
        if (gid < T_ * B_ * 3) {
            int t = gid / (B_ * 3);
            int b = (gid / 3) % B_;
            int r = gid % 3;
            float v = rm[t * B_ * 16 + b * 16 + r * 4 + 3];
            atr = v * v;
        }
        float acc = apd * (1.0f / B_) + asp * (1.0f / (B_ * N_)) + atr * (1.0f / B_);
        float s = block_reduce<4>(acc, red);
        if (threadIdx.x == 0) atomicAdd(out, s);
    }
}

// ---------------------------------------------------------------------------
extern "C" void kernel_launch(void* const* d_in, const int* in_sizes, int n_in,
                              void* d_out, int out_size, void* d_ws, size_t ws_size,
                              hipStream_t stream) {
    const float* pw  = (const float*)d_in[1];
    const float* drp = (const float*)d_in[2];
    const float* dp  = (const float*)d_in[3];
    const float* rm  = (const float*)d_in[4];
    const float* sp  = (const float*)d_in[5];
    const float* tp  = (const float*)d_in[6];
    float* out = (float*)d_out;

    int*      idx  = (int*)d_ws;                                           // 512 KiB
    unsigned* cmin = (unsigned*)((char*)d_ws + (size_t)B_ * N_ * K_ * 4);  // 384 KiB

    knn_kernel<<<B_ * (N_ / KQPB), 256, 0, stream>>>(sp, idx, cmin, out);
    chamfer_kernel<<<T_ * B_ * 2 * 2 * CCH, 256, 0, stream>>>(dp, tp, cmin);
    finalize_kernel<<<608, 256, 0, stream>>>(dp, tp, sp, idx, cmin, drp, pw, rm, out);
}

// Round 5
// 144.058 us; speedup vs baseline: 5.9659x; 1.0842x over previous
//
#include <hip/hip_runtime.h>

#define T_ 3
#define B_ 4
#define N_ 4096
#define K_ 8

// ---------------------------------------------------------------------------
template <int NW>
__device__ inline float block_reduce(float v, float* scratch) {
    #pragma unroll
    for (int off = 32; off > 0; off >>= 1) v += __shfl_down(v, off, 64);
    const int lane = threadIdx.x & 63, wid = threadIdx.x >> 6;
    if (lane == 0) scratch[wid] = v;
    __syncthreads();
    float s = 0.f;
    if (threadIdx.x == 0) {
        #pragma unroll
        for (int w = 0; w < NW; ++w) s += scratch[w];
    }
    return s;  // valid on thread 0 only
}

__device__ inline unsigned f2sortable(float f) {
    unsigned b = __float_as_uint(f);
    return b ^ ((unsigned)((int)b >> 31) | 0x80000000u);
}
__device__ inline float sortable2f(unsigned u) {
    unsigned b = (u & 0x80000000u) ? (u ^ 0x80000000u) : ~u;
    return __uint_as_float(b);
}

// Batcher odd-even 8-sort (19 CEs) — independent of running list (ILP).
#define CE_(A, i, j) { unsigned lo_ = min(A[i], A[j]); A[j] = max(A[i], A[j]); A[i] = lo_; }
__device__ inline void sort8(unsigned s[8]) {
    CE_(s,0,1) CE_(s,2,3) CE_(s,4,5) CE_(s,6,7)
    CE_(s,0,2) CE_(s,1,3) CE_(s,4,6) CE_(s,5,7)
    CE_(s,1,2) CE_(s,5,6)
    CE_(s,0,4) CE_(s,1,5) CE_(s,2,6) CE_(s,3,7)
    CE_(s,2,4) CE_(s,3,5)
    CE_(s,1,2) CE_(s,3,4) CE_(s,5,6)
}
// a (asc) := lowest-8 of union(a asc, s asc), sorted. Half-clean + bitonic merge.
__device__ inline void merge_top8(unsigned a[8], const unsigned s[8]) {
    #pragma unroll
    for (int i = 0; i < 8; ++i) a[i] = min(a[i], s[7 - i]);  // bitonic, lowest 8
    CE_(a,0,4) CE_(a,1,5) CE_(a,2,6) CE_(a,3,7)
    CE_(a,0,2) CE_(a,1,3) CE_(a,4,6) CE_(a,5,7)
    CE_(a,0,1) CE_(a,2,3) CE_(a,4,5) CE_(a,6,7)
}

// ---------------------------------------------------------------------------
// KNN v5: 8 queries x 32 residue classes per block -> 2048 blocks (8/CU).
// Candidates streamed in 4 windows of 1024 (16 KiB LDS). Per thread: 128
// candidates (j == c mod 32) in 16 batches of 8: sort8 (independent) +
// merge_top8 (short carried chain). In-block 5-stage tree merge over classes.
// Packed sortable key: (dist_bits & 0xFFFFF000) | j. Also inits cmin/out.
#define KQPB 8
#define KWIN 1024

__global__ __launch_bounds__(256, 8) void knn_kernel(const float* __restrict__ src,
                                                     int* __restrict__ idx,
                                                     unsigned* __restrict__ cmin,
                                                     float* __restrict__ out) {
    __shared__ float4 win[KWIN];  // 16 KiB
    const int g = blockIdx.x * 256 + threadIdx.x;
    if (g < T_ * B_ * 2 * N_) cmin[g] = 0xFFFFFFFFu;  // init for chamfer
    if (g == 0) *out = 0.f;

    const int b  = blockIdx.x / (N_ / KQPB);
    const int q0 = (blockIdx.x % (N_ / KQPB)) * KQPB;
    const float* sb = src + (size_t)b * N_ * 3;

    const int lq = threadIdx.x >> 5;  // query slot 0..7
    const int c  = threadIdx.x & 31;  // residue class 0..31
    const int i  = q0 + lq;
    const float qx = sb[3 * i], qy = sb[3 * i + 1], qz = sb[3 * i + 2];
    const float q2 = fmaf(qx, qx, fmaf(qy, qy, qz * qz));

    unsigned a[K_];
    #pragma unroll
    for (int p = 0; p < K_; ++p) a[p] = 0xFFFFFFFFu;

    for (int w = 0; w < N_ / KWIN; ++w) {
        __syncthreads();
        for (int j = threadIdx.x; j < KWIN; j += 256) {
            int jg = w * KWIN + j;
            float x = sb[3 * jg], y = sb[3 * jg + 1], z = sb[3 * jg + 2];
            win[j] = make_float4(-2.f * x, -2.f * y, -2.f * z, fmaf(x, x, fmaf(y, y, z * z)));
        }
        __syncthreads();

        #pragma unroll
        for (int bt = 0; bt < KWIN / 8 / 32; ++bt) {  // 4 batches of 8
            unsigned s[8];
            #pragma unroll
            for (int u = 0; u < 8; ++u) {
                int jl = 32 * (bt * 8 + u) + c;
                float4 cd = win[jl];
                float d = fmaf(qx, cd.x, fmaf(qy, cd.y, fmaf(qz, cd.z, cd.w))) + q2;  // >= 0
                int jglob = w * KWIN + jl;
                unsigned pu = (__float_as_uint(d) & 0xFFFFF000u) | (unsigned)jglob;
                s[u] = (jglob == i) ? 0xFFFFFFFFu : pu;  // exclude self
            }
            sort8(s);
            merge_top8(a, s);
        }
    }
    __syncthreads();

    // Tree merge across the 32 classes. Slot(e,c,q) = 288e + 9c + q
    // (stride 9 -> unique addrs, <=2-way bank alias = free). 9.1 KiB in win.
    unsigned* sm = (unsigned*)win;
    for (int half = 16; half >= 1; half >>= 1) {
        #pragma unroll
        for (int e = 0; e < K_; ++e) sm[288 * e + 9 * c + lq] = a[e];
        __syncthreads();
        if (c < half) {
            unsigned s[8];
            #pragma unroll
            for (int e = 0; e < K_; ++e) s[e] = sm[288 * e + 9 * (c + half) + lq];
            merge_top8(a, s);
        }
        __syncthreads();
    }

    if (c == 0) {
        int* op = idx + ((size_t)b * N_ + q0 + lq) * K_;
        #pragma unroll
        for (int k = 0; k < K_; ++k) op[k] = (int)(a[k] & 0xFFFu);
    }
}

// ---------------------------------------------------------------------------
// Chamfer: 4 queries/thread, 128-candidate chunks (2 KiB LDS), grid 3072
// (12 blocks/CU). Partial mins of (|c|^2 - 2 q.c) via atomicMin on sortable.
#define CCH 32
#define CCHSZ (N_ / CCH)  // 128
#define CQ 4

__global__ __launch_bounds__(256, 8) void chamfer_kernel(const float* __restrict__ dp_all,
                                                         const float* __restrict__ tp,
                                                         unsigned* __restrict__ cmin) {
    __shared__ float4 pts[CCHSZ];  // 2 KiB
    int blk = blockIdx.x;
    const int cc = blk & (CCH - 1); blk >>= 5;
    const int qc = blk & 3;         blk >>= 2;
    const int tbd = blk;            // ((t*B+b)*2+dir)
    const int dir = tbd & 1;
    const int tb  = tbd >> 1;
    const int b = tb % B_, t = tb / B_;

    const float* dpb = dp_all + ((size_t)(t * B_ + b)) * N_ * 3;
    const float* tpb = tp + (size_t)b * N_ * 3;
    const float* dbase = dir ? dpb : tpb;  // candidates
    const float* qbase = dir ? tpb : dpb;  // queries

    if (threadIdx.x < CCHSZ) {
        int jg = cc * CCHSZ + threadIdx.x;
        float x = dbase[3 * jg], y = dbase[3 * jg + 1], z = dbase[3 * jg + 2];
        pts[threadIdx.x] = make_float4(-2.f * x, -2.f * y, -2.f * z,
                                       fmaf(x, x, fmaf(y, y, z * z)));
    }
    __syncthreads();

    float qx[CQ], qy[CQ], qz[CQ], m[CQ];
    #pragma unroll
    for (int u = 0; u < CQ; ++u) {
        int q = qc * 1024 + u * 256 + threadIdx.x;
        qx[u] = qbase[3 * q]; qy[u] = qbase[3 * q + 1]; qz[u] = qbase[3 * q + 2];
        m[u] = 3.4e38f;
    }
    #pragma unroll 4
    for (int j = 0; j < CCHSZ; ++j) {
        float4 cd = pts[j];  // wave-uniform -> LDS broadcast
        #pragma unroll
        for (int u = 0; u < CQ; ++u)
            m[u] = fminf(m[u], fmaf(qx[u], cd.x, fmaf(qy[u], cd.y, fmaf(qz[u], cd.z, cd.w))));
    }
    unsigned* cm = cmin + (size_t)tbd * N_ + qc * 1024;
    #pragma unroll
    for (int u = 0; u < CQ; ++u)
        atomicMin(&cm[u * 256 + threadIdx.x], f2sortable(m[u]));
}

// ---------------------------------------------------------------------------
// Finalize: block roles: [0,384) chamfer merge; [384,576) arap; [576,608) rest.
__global__ __launch_bounds__(256) void finalize_kernel(const float* __restrict__ dp_all,
                                                       const float* __restrict__ tp,
                                                       const float* __restrict__ src,
                                                       const int* __restrict__ idx,
                                                       const unsigned* __restrict__ cmin,
                                                       const float* __restrict__ drp,
                                                       const float* __restrict__ pw,
                                                       const float* __restrict__ rm,
                                                       float* __restrict__ out) {
    __shared__ float red[4];
    const int blk = blockIdx.x;

    if (blk < 384) {  // ---- chamfer merge: add |q|^2, reduce
        const int tbd = blk >> 4;
        const int q = (blk & 15) * 256 + threadIdx.x;
        const int dir = tbd & 1, tb = tbd >> 1, b = tb % B_, t = tb / B_;
        const float* qbase = dir ? tp + (size_t)b * N_ * 3
                                 : dp_all + ((size_t)(t * B_ + b)) * N_ * 3;
        float mrel = sortable2f(cmin[(size_t)tbd * N_ + q]);
        float x = qbase[3 * q], y = qbase[3 * q + 1], z = qbase[3 * q + 2];
        float v = fmaf(x, x, fmaf(y, y, z * z)) + mrel;
        float s = block_reduce<4>(v, red);
        if (threadIdx.x == 0) atomicAdd(out, s * (0.5f / B_));
    } else if (blk < 576) {  // ---- arap
        const int ab = blk - 384;
        const int chunk = ab & 15;
        const int tb = ab >> 4;
        const int b = tb % B_, t = tb / B_;
        const int n = chunk * 256 + threadIdx.x;
        const float* dp = dp_all + ((size_t)t * B_ + b) * (N_ * 3);
        const float* sp = src + (size_t)b * (N_ * 3);
        const float px = dp[n * 3], py = dp[n * 3 + 1], pz = dp[n * 3 + 2];
        const float sx = sp[n * 3], sy = sp[n * 3 + 1], sz = sp[n * 3 + 2];
        const int* ip = idx + ((size_t)b * N_ + n) * K_;
        float acc = 0.f;
        #pragma unroll
        for (int k = 0; k < K_; ++k) {
            int j = ip[k];
            float dx = dp[j * 3] - px, dy = dp[j * 3 + 1] - py, dz = dp[j * 3 + 2] - pz;
            float ex = sp[j * 3] - sx, ey = sp[j * 3 + 1] - sy, ez = sp[j * 3 + 2] - sz;
            float dd = sqrtf(fmaf(dx, dx, fmaf(dy, dy, dz * dz)) + 1e-5f);
            float sd = sqrtf(fmaf(ex, ex, fmaf(ey, ey, ez * ez)) + 1e-5f);
            float df = dd - sd;
            acc = fmaf(df, df, acc);
        }
        float s = block_reduce<4>(acc, red);
        if (threadIdx.x == 0) atomicAdd(out, s * (1.0f / B_));
    } else {  // ---- pd + sp + tran
        const int PD_N = T_ * B_ * N_ * 3;
        const int SP_N = T_ * B_ * N_;
        const int stride = 32 * 256;
        const int gid = (blk - 576) * 256 + threadIdx.x;
        float apd = 0.f;
        for (int i = gid; i < PD_N; i += stride) {
            float d = drp[i] - dp_all[i];
            apd = fmaf(d, d, apd);
        }
        float asp = 0.f;
        for (int i = gid; i < SP_N; i += stride) asp += fabsf(pw[i]);
        float atr = 0.f;
        if (gid < T_ * B_ * 3) {
            int t = gid / (B_ * 3);
            int b = (gid / 3) % B_;
            int r = gid % 3;
            float v = rm[t * B_ * 16 + b * 16 + r * 4 + 3];
            atr = v * v;
        }
        float acc = apd * (1.0f / B_) + asp * (1.0f / (B_ * N_)) + atr * (1.0f / B_);
        float s = block_reduce<4>(acc, red);
        if (threadIdx.x == 0) atomicAdd(out, s);
    }
}

// ---------------------------------------------------------------------------
extern "C" void kernel_launch(void* const* d_in, const int* in_sizes, int n_in,
                              void* d_out, int out_size, void* d_ws, size_t ws_size,
                              hipStream_t stream) {
    const float* pw  = (const float*)d_in[1];
    const float* drp = (const float*)d_in[2];
    const float* dp  = (const float*)d_in[3];
    const float* rm  = (const float*)d_in[4];
    const float* sp  = (const float*)d_in[5];
    const float* tp  = (const float*)d_in[6];
    float* out = (float*)d_out;

    int*      idx  = (int*)d_ws;                                           // 512 KiB
    unsigned* cmin = (unsigned*)((char*)d_ws + (size_t)B_ * N_ * K_ * 4);  // 384 KiB

    knn_kernel<<<B_ * (N_ / KQPB), 256, 0, stream>>>(sp, idx, cmin, out);
    chamfer_kernel<<<T_ * B_ * 2 * 4 * CCH, 256, 0, stream>>>(dp, tp, cmin);
    finalize_kernel<<<608, 256, 0, stream>>>(dp, tp, sp, idx, cmin, drp, pw, rm, out);
}

// Round 6
// 131.300 us; speedup vs baseline: 6.5455x; 1.0972x over previous
//
#include <hip/hip_runtime.h>

#define T_ 3
#define B_ 4
#define N_ 4096
#define K_ 8

// mega-kernel geometry
#define KNN_BLOCKS (B_ * (N_ / 16))           // 1024 : knn role, 16 queries/block
#define CH_CCH     32                         // candidate chunks of 128
#define CH_CHSZ    (N_ / CH_CCH)              // 128
#define CH_CQ      8                          // queries per thread
#define CH_BLOCKS  (T_ * B_ * 2 * 2 * CH_CCH) // 1536

// ---------------------------------------------------------------------------
template <int NW>
__device__ inline float block_reduce(float v, float* scratch) {
    #pragma unroll
    for (int off = 32; off > 0; off >>= 1) v += __shfl_down(v, off, 64);
    const int lane = threadIdx.x & 63, wid = threadIdx.x >> 6;
    if (lane == 0) scratch[wid] = v;
    __syncthreads();
    float s = 0.f;
    if (threadIdx.x == 0) {
        #pragma unroll
        for (int w = 0; w < NW; ++w) s += scratch[w];
    }
    return s;  // valid on thread 0 only
}

// Batcher odd-even 8-sort (19 CEs) — independent of running list (ILP).
#define CE_(A, i, j) { unsigned lo_ = min(A[i], A[j]); A[j] = max(A[i], A[j]); A[i] = lo_; }
__device__ inline void sort8(unsigned s[8]) {
    CE_(s,0,1) CE_(s,2,3) CE_(s,4,5) CE_(s,6,7)
    CE_(s,0,2) CE_(s,1,3) CE_(s,4,6) CE_(s,5,7)
    CE_(s,1,2) CE_(s,5,6)
    CE_(s,0,4) CE_(s,1,5) CE_(s,2,6) CE_(s,3,7)
    CE_(s,2,4) CE_(s,3,5)
    CE_(s,1,2) CE_(s,3,4) CE_(s,5,6)
}
// a (asc) := lowest-8 of union(a asc, s asc), sorted. Half-clean + bitonic merge.
__device__ inline void merge_top8(unsigned a[8], const unsigned s[8]) {
    #pragma unroll
    for (int i = 0; i < 8; ++i) a[i] = min(a[i], s[7 - i]);  // bitonic, lowest 8
    CE_(a,0,4) CE_(a,1,5) CE_(a,2,6) CE_(a,3,7)
    CE_(a,0,2) CE_(a,1,3) CE_(a,4,6) CE_(a,5,7)
    CE_(a,0,1) CE_(a,2,3) CE_(a,4,5) CE_(a,6,7)
}

// ---------------------------------------------------------------------------
// Mega kernel: blocks [0,1024) = KNN role, [1024,2560) = chamfer role.
//
// KNN role: 16 queries/block as 8 query-PAIRS x 32 residue classes; each
// thread serves 2 queries over 128 candidates (j == c mod 32), so one
// ds_read_b128 feeds 2 distance computations (halves LDS-pipe load vs v5).
// Batched sort8 + bitonic merge keeps the loop-carried chain short.
// Packed sortable key: (dist_bits & 0xFFFFF000) | j.
//
// Chamfer role: 8 queries/thread vs one 128-candidate chunk; writes raw
// per-chunk partial mins of (|c|^2 - 2 q.c) to pmin[tbd][cc][q] (no atomics,
// no init needed -> lets knn+chamfer share one launch).
#define KWIN 1024

__global__ __launch_bounds__(256, 6) void mega_kernel(const float* __restrict__ src,
                                                      const float* __restrict__ dp_all,
                                                      const float* __restrict__ tp,
                                                      int* __restrict__ idx,
                                                      float* __restrict__ pmin,
                                                      float* __restrict__ out) {
    __shared__ unsigned smem_u[4352];  // 17 KiB: window(16K) / merge scratch(17K) / chamfer(2K)
    if (blockIdx.x == 0 && threadIdx.x == 0) *out = 0.f;

    if (blockIdx.x < KNN_BLOCKS) {  // ================= KNN role
        float4* win = (float4*)smem_u;
        const int b  = blockIdx.x / (N_ / 16);
        const int q0 = (blockIdx.x % (N_ / 16)) * 16;
        const float* sb = src + (size_t)b * N_ * 3;

        const int qp = threadIdx.x >> 5;  // query pair 0..7
        const int c  = threadIdx.x & 31;  // residue class 0..31
        const int i0 = q0 + 2 * qp, i1 = i0 + 1;
        const float qx0 = sb[3 * i0], qy0 = sb[3 * i0 + 1], qz0 = sb[3 * i0 + 2];
        const float qx1 = sb[3 * i1], qy1 = sb[3 * i1 + 1], qz1 = sb[3 * i1 + 2];
        const float q20 = fmaf(qx0, qx0, fmaf(qy0, qy0, qz0 * qz0));
        const float q21 = fmaf(qx1, qx1, fmaf(qy1, qy1, qz1 * qz1));

        unsigned a0[K_], a1[K_];
        #pragma unroll
        for (int p = 0; p < K_; ++p) { a0[p] = 0xFFFFFFFFu; a1[p] = 0xFFFFFFFFu; }

        for (int w = 0; w < N_ / KWIN; ++w) {
            __syncthreads();
            for (int j = threadIdx.x; j < KWIN; j += 256) {
                int jg = w * KWIN + j;
                float x = sb[3 * jg], y = sb[3 * jg + 1], z = sb[3 * jg + 2];
                win[j] = make_float4(-2.f * x, -2.f * y, -2.f * z,
                                     fmaf(x, x, fmaf(y, y, z * z)));
            }
            __syncthreads();

            #pragma unroll
            for (int bt = 0; bt < KWIN / 8 / 32; ++bt) {  // 4 batches of 8
                unsigned s0[8], s1[8];
                #pragma unroll
                for (int u = 0; u < 8; ++u) {
                    int jl = 32 * (bt * 8 + u) + c;
                    float4 cd = win[jl];
                    int jglob = w * KWIN + jl;
                    float d0 = fmaf(qx0, cd.x, fmaf(qy0, cd.y, fmaf(qz0, cd.z, cd.w))) + q20;
                    float d1 = fmaf(qx1, cd.x, fmaf(qy1, cd.y, fmaf(qz1, cd.z, cd.w))) + q21;
                    unsigned p0 = (__float_as_uint(d0) & 0xFFFFF000u) | (unsigned)jglob;
                    unsigned p1 = (__float_as_uint(d1) & 0xFFFFF000u) | (unsigned)jglob;
                    s0[u] = (jglob == i0) ? 0xFFFFFFFFu : p0;  // exclude self
                    s1[u] = (jglob == i1) ? 0xFFFFFFFFu : p1;
                }
                sort8(s0); merge_top8(a0, s0);
                sort8(s1); merge_top8(a1, s1);
            }
        }
        __syncthreads();

        // Tree merge across the 32 classes. Slot(e,cls,q) = (e*32+cls)*17 + q
        // (17 odd -> bank permutation across cls, conflict-free).
        unsigned* sm = smem_u;
        for (int half = 16; half >= 1; half >>= 1) {
            #pragma unroll
            for (int e = 0; e < K_; ++e) {
                sm[(e * 32 + c) * 17 + 2 * qp]     = a0[e];
                sm[(e * 32 + c) * 17 + 2 * qp + 1] = a1[e];
            }
            __syncthreads();
            if (c < half) {
                unsigned t0[8], t1[8];
                #pragma unroll
                for (int e = 0; e < K_; ++e) {
                    t0[e] = sm[(e * 32 + c + half) * 17 + 2 * qp];
                    t1[e] = sm[(e * 32 + c + half) * 17 + 2 * qp + 1];
                }
                merge_top8(a0, t0);
                merge_top8(a1, t1);
            }
            __syncthreads();
        }

        if (c == 0) {
            int* op0 = idx + ((size_t)b * N_ + i0) * K_;
            int* op1 = idx + ((size_t)b * N_ + i1) * K_;
            #pragma unroll
            for (int k = 0; k < K_; ++k) {
                op0[k] = (int)(a0[k] & 0xFFFu);
                op1[k] = (int)(a1[k] & 0xFFFu);
            }
        }
    } else {  // ================= chamfer role
        float4* pts = (float4*)smem_u;  // 2 KiB slice
        int blk = blockIdx.x - KNN_BLOCKS;
        const int cc = blk & (CH_CCH - 1); blk >>= 5;
        const int qc = blk & 1;            blk >>= 1;
        const int tbd = blk;               // ((t*B+b)*2+dir)
        const int dir = tbd & 1;
        const int tb  = tbd >> 1;
        const int b = tb % B_, t = tb / B_;

        const float* dpb = dp_all + ((size_t)(t * B_ + b)) * N_ * 3;
        const float* tpb = tp + (size_t)b * N_ * 3;
        const float* dbase = dir ? dpb : tpb;  // candidates
        const float* qbase = dir ? tpb : dpb;  // queries

        if (threadIdx.x < CH_CHSZ) {
            int jg = cc * CH_CHSZ + threadIdx.x;
            float x = dbase[3 * jg], y = dbase[3 * jg + 1], z = dbase[3 * jg + 2];
            pts[threadIdx.x] = make_float4(-2.f * x, -2.f * y, -2.f * z,
                                           fmaf(x, x, fmaf(y, y, z * z)));
        }
        __syncthreads();

        float qx[CH_CQ], qy[CH_CQ], qz[CH_CQ], m[CH_CQ];
        #pragma unroll
        for (int u = 0; u < CH_CQ; ++u) {
            int q = qc * 2048 + u * 256 + threadIdx.x;
            qx[u] = qbase[3 * q]; qy[u] = qbase[3 * q + 1]; qz[u] = qbase[3 * q + 2];
            m[u] = 3.4e38f;
        }
        #pragma unroll 2
        for (int j = 0; j < CH_CHSZ; ++j) {
            float4 cd = pts[j];  // wave-uniform -> LDS broadcast
            #pragma unroll
            for (int u = 0; u < CH_CQ; ++u)
                m[u] = fminf(m[u], fmaf(qx[u], cd.x, fmaf(qy[u], cd.y, fmaf(qz[u], cd.z, cd.w))));
        }
        float* pm = pmin + ((size_t)tbd * CH_CCH + cc) * N_ + qc * 2048;
        #pragma unroll
        for (int u = 0; u < CH_CQ; ++u)
            pm[u * 256 + threadIdx.x] = m[u];  // one writer per slot, no init needed
    }
}

// ---------------------------------------------------------------------------
// Finalize: block roles: [0,384) chamfer merge; [384,576) arap; [576,608) rest.
__global__ __launch_bounds__(256) void finalize_kernel(const float* __restrict__ dp_all,
                                                       const float* __restrict__ tp,
                                                       const float* __restrict__ src,
                                                       const int* __restrict__ idx,
                                                       const float* __restrict__ pmin,
                                                       const float* __restrict__ drp,
                                                       const float* __restrict__ pw,
                                                       const float* __restrict__ rm,
                                                       float* __restrict__ out) {
    __shared__ float red[4];
    const int blk = blockIdx.x;

    if (blk < 384) {  // ---- chamfer merge: 32-way min + |q|^2, reduce
        const int tbd = blk >> 4;
        const int q = (blk & 15) * 256 + threadIdx.x;
        const int dir = tbd & 1, tb = tbd >> 1, b = tb % B_, t = tb / B_;
        const float* qbase = dir ? tp + (size_t)b * N_ * 3
                                 : dp_all + ((size_t)(t * B_ + b)) * N_ * 3;
        float mrel = 3.4e38f;
        #pragma unroll
        for (int cc = 0; cc < CH_CCH; ++cc)
            mrel = fminf(mrel, pmin[((size_t)tbd * CH_CCH + cc) * N_ + q]);
        float x = qbase[3 * q], y = qbase[3 * q + 1], z = qbase[3 * q + 2];
        float v = fmaf(x, x, fmaf(y, y, z * z)) + mrel;
        float s = block_reduce<4>(v, red);
        if (threadIdx.x == 0) atomicAdd(out, s * (0.5f / B_));
    } else if (blk < 576) {  // ---- arap
        const int ab = blk - 384;
        const int chunk = ab & 15;
        const int tb = ab >> 4;
        const int b = tb % B_, t = tb / B_;
        const int n = chunk * 256 + threadIdx.x;
        const float* dp = dp_all + ((size_t)t * B_ + b) * (N_ * 3);
        const float* sp = src + (size_t)b * (N_ * 3);
        const float px = dp[n * 3], py = dp[n * 3 + 1], pz = dp[n * 3 + 2];
        const float sx = sp[n * 3], sy = sp[n * 3 + 1], sz = sp[n * 3 + 2];
        const int* ip = idx + ((size_t)b * N_ + n) * K_;
        float acc = 0.f;
        #pragma unroll
        for (int k = 0; k < K_; ++k) {
            int j = ip[k];
            float dx = dp[j * 3] - px, dy = dp[j * 3 + 1] - py, dz = dp[j * 3 + 2] - pz;
            float ex = sp[j * 3] - sx, ey = sp[j * 3 + 1] - sy, ez = sp[j * 3 + 2] - sz;
            float dd = sqrtf(fmaf(dx, dx, fmaf(dy, dy, dz * dz)) + 1e-5f);
            float sd = sqrtf(fmaf(ex, ex, fmaf(ey, ey, ez * ez)) + 1e-5f);
            float df = dd - sd;
            acc = fmaf(df, df, acc);
        }
        float s = block_reduce<4>(acc, red);
        if (threadIdx.x == 0) atomicAdd(out, s * (1.0f / B_));
    } else {  // ---- pd + sp + tran
        const int PD_N = T_ * B_ * N_ * 3;
        const int SP_N = T_ * B_ * N_;
        const int stride = 32 * 256;
        const int gid = (blk - 576) * 256 + threadIdx.x;
        float apd = 0.f;
        for (int i = gid; i < PD_N; i += stride) {
            float d = drp[i] - dp_all[i];
            apd = fmaf(d, d, apd);
        }
        float asp = 0.f;
        for (int i = gid; i < SP_N; i += stride) asp += fabsf(pw[i]);
        float atr = 0.f;
        if (gid < T_ * B_ * 3) {
            int t = gid / (B_ * 3);
            int b = (gid / 3) % B_;
            int r = gid % 3;
            float v = rm[t * B_ * 16 + b * 16 + r * 4 + 3];
            atr = v * v;
        }
        float acc = apd * (1.0f / B_) + asp * (1.0f / (B_ * N_)) + atr * (1.0f / B_);
        float s = block_reduce<4>(acc, red);
        if (threadIdx.x == 0) atomicAdd(out, s);
    }
}

// ---------------------------------------------------------------------------
extern "C" void kernel_launch(void* const* d_in, const int* in_sizes, int n_in,
                              void* d_out, int out_size, void* d_ws, size_t ws_size,
                              hipStream_t stream) {
    const float* pw  = (const float*)d_in[1];
    const float* drp = (const float*)d_in[2];
    const float* dp  = (const float*)d_in[3];
    const float* rm  = (const float*)d_in[4];
    const float* sp  = (const float*)d_in[5];
    const float* tp  = (const float*)d_in[6];
    float* out = (float*)d_out;

    int*   idx  = (int*)d_ws;                                          // 512 KiB
    float* pmin = (float*)((char*)d_ws + (size_t)B_ * N_ * K_ * 4);    // 24*32*4096*4 = 12.6 MiB

    mega_kernel<<<KNN_BLOCKS + CH_BLOCKS, 256, 0, stream>>>(sp, dp, tp, idx, pmin, out);
    finalize_kernel<<<608, 256, 0, stream>>>(dp, tp, sp, idx, pmin, drp, pw, rm, out);
}